// Round 1
// baseline (367.604 us; speedup 1.0000x reference)
//
#include <hip/hip_runtime.h>

// Row-wise gating one-hot: selected = trend>0.5 ? 0 : (cycle>high ? 1 : 2)
// features: (N, 16) f32 row-major; out: (N, 3) f32.
// 4 rows per thread -> 12 output floats = 3 aligned float4 stores.
__global__ __launch_bounds__(256) void gating_kernel(
    const float* __restrict__ feat, float* __restrict__ out, int nquads) {
    int t = blockIdx.x * blockDim.x + threadIdx.x;
    if (t >= nquads) return;

    float w[12];
#pragma unroll
    for (int r = 0; r < 4; ++r) {
        long long row = 4LL * t + r;
        const float* fr = feat + row * 16;
        // cols 4..7 as one 16B load (row base is 64B aligned, +16B stays 16B aligned)
        float4 c47 = *reinterpret_cast<const float4*>(fr + 4);
        float trend = fr[11];

        bool s0 = trend > 0.5f;                       // expert 0
        bool s1 = (c47.x + c47.y) > (c47.z + c47.w);  // expert 1 vs 2

        w[3 * r + 0] = s0 ? 1.0f : 0.0f;
        w[3 * r + 1] = (!s0 && s1) ? 1.0f : 0.0f;
        w[3 * r + 2] = (!s0 && !s1) ? 1.0f : 0.0f;
    }

    float4* ob = reinterpret_cast<float4*>(out + 12LL * t);
    ob[0] = make_float4(w[0], w[1], w[2], w[3]);
    ob[1] = make_float4(w[4], w[5], w[6], w[7]);
    ob[2] = make_float4(w[8], w[9], w[10], w[11]);
}

extern "C" void kernel_launch(void* const* d_in, const int* in_sizes, int n_in,
                              void* d_out, int out_size, void* d_ws, size_t ws_size,
                              hipStream_t stream) {
    const float* feat = (const float*)d_in[0];
    float* out = (float*)d_out;

    const int n_rows = in_sizes[0] / 16;   // 4194304
    const int nquads = n_rows / 4;         // 1048576 (N divisible by 4)

    const int block = 256;
    const int grid = (nquads + block - 1) / block;  // 4096
    gating_kernel<<<grid, block, 0, stream>>>(feat, out, nquads);
}

// Round 2
// 362.113 us; speedup vs baseline: 1.0152x; 1.0152x over previous
//
#include <hip/hip_runtime.h>

// Streaming read + LDS redistribute.
// Block = 256 threads = 256 rows = 1024 float4 (16 KiB in, 3 KiB out).
// Load phase: thread t loads float4 g = t + k*256 (k=0..3) -> fully coalesced
//   1 KiB/wave-instr. part p = g&3 (uniform per thread since 256%4==0):
//   p==1 -> cols 4..7 -> diff = (c4+c5)-(c6+c7); p==2 -> col11 = .w -> trend.
// Compute: row t one-hot -> LDS; flush 192 float4 coalesced stores.
__global__ __launch_bounds__(256) void gating_kernel(
    const float* __restrict__ feat, float* __restrict__ out, int n_rows) {
    __shared__ float s_diff[256];
    __shared__ float s_trend[256];
    __shared__ float s_out[768];

    const int t = threadIdx.x;
    const int block_row0 = blockIdx.x * 256;   // n_rows % 256 == 0 (4194304)
    const float4* in4 = reinterpret_cast<const float4*>(feat) + (size_t)block_row0 * 4;

    const int p = t & 3;  // float4 part within row, uniform across k
#pragma unroll
    for (int k = 0; k < 4; ++k) {
        const int g = t + k * 256;       // float4 index within block tile
        const float4 v = in4[g];
        const int r = g >> 2;            // row within block tile
        if (p == 1) s_diff[r]  = (v.x + v.y) - (v.z + v.w);   // cols 4..7
        if (p == 2) s_trend[r] = v.w;                          // col 11
    }
    __syncthreads();

    const bool s0 = s_trend[t] > 0.5f;
    const bool s1 = s_diff[t] > 0.0f;
    s_out[3 * t + 0] = s0 ? 1.0f : 0.0f;
    s_out[3 * t + 1] = (!s0 && s1) ? 1.0f : 0.0f;
    s_out[3 * t + 2] = (!s0 && !s1) ? 1.0f : 0.0f;
    __syncthreads();

    if (t < 192) {
        float4* ob = reinterpret_cast<float4*>(out + (size_t)block_row0 * 3);
        ob[t] = reinterpret_cast<const float4*>(s_out)[t];
    }
}

extern "C" void kernel_launch(void* const* d_in, const int* in_sizes, int n_in,
                              void* d_out, int out_size, void* d_ws, size_t ws_size,
                              hipStream_t stream) {
    const float* feat = (const float*)d_in[0];
    float* out = (float*)d_out;

    const int n_rows = in_sizes[0] / 16;       // 4194304, divisible by 256
    const int grid = n_rows / 256;             // 16384 blocks

    gating_kernel<<<grid, 256, 0, stream>>>(feat, out, n_rows);
}